// Round 11
// baseline (199.087 us; speedup 1.0000x reference)
//
#include <hip/hip_runtime.h>
#include <cstdint>
#include <type_traits>

#define BATCH  2
#define SEQ    2048
#define DM     1024
#define NH     16
#define DH     64
#define MR     (BATCH*SEQ)   // 4096 rows

typedef float  f32x4  __attribute__((ext_vector_type(4)));
typedef short  s16x8  __attribute__((ext_vector_type(8)));
typedef unsigned short u16x4 __attribute__((ext_vector_type(4)));
typedef unsigned short u16x8 __attribute__((ext_vector_type(8)));
typedef __bf16 bf16x8 __attribute__((ext_vector_type(8)));

// ---- mfma arg-type detection: accept whichever signature this clang has ----
template <typename V, typename = void> struct mfma_ok : std::false_type {};
template <typename V>
struct mfma_ok<V, std::void_t<decltype(__builtin_amdgcn_mfma_f32_16x16x32_bf16(
    std::declval<V>(), std::declval<V>(), std::declval<f32x4>(), 0, 0, 0))>>
    : std::true_type {};
using frag_t = std::conditional_t<mfma_ok<bf16x8>::value, bf16x8, s16x8>;
static_assert(mfma_ok<frag_t>::value, "no usable mfma bf16 fragment type");

template <typename V>
__device__ inline f32x4 mfma_16x16x32_bf16(V a, V b, f32x4 c) {
  return __builtin_amdgcn_mfma_f32_16x16x32_bf16(a, b, c, 0, 0, 0);
}

__device__ inline uint16_t f2b(float f) {   // RNE f32 -> bf16 bits
  union { float f; uint32_t u; } v; v.f = f;
  return (uint16_t)((v.u + 0x7fffu + ((v.u >> 16) & 1u)) >> 16);
}

// packed 2xf32 -> 2xbf16 (low=a, high=b); HW pk instr on gfx950 if available
#if defined(__has_builtin)
#if __has_builtin(__builtin_amdgcn_cvt_pk_bf16_f32)
#define HAVE_PK_BF16 1
#endif
#endif
__device__ inline uint32_t f2b2(float a, float b) {
#ifdef HAVE_PK_BF16
  auto r = __builtin_amdgcn_cvt_pk_bf16_f32(a, b);
  static_assert(sizeof(r) == 4, "pk_bf16 must be 4 bytes");
  union { decltype(r) v; uint32_t u; } c; c.v = r; return c.u;
#else
  return (uint32_t)f2b(a) | ((uint32_t)f2b(b) << 16);
#endif
}

// ------- fused prep: weight transpose 64x64 (blocks 0..1023) + x cast -------
__global__ __launch_bounds__(256) void prep_all(
    const float* __restrict__ w0, const float* __restrict__ w1,
    const float* __restrict__ w2, const float* __restrict__ w3,
    uint16_t* __restrict__ wtout,
    const float* __restrict__ x, uint16_t* __restrict__ xb)
{
  const int bid = blockIdx.x;
  const int t = threadIdx.x;
  if (bid < 1024) {
    __shared__ uint16_t tile[64][65];
    const int z = bid >> 8, rem = bid & 255;
    const int by = rem >> 4, bx = rem & 15;   // by: k-tile, bx: n-tile
    const int tx = t & 63, ty = t >> 6;
    const float* W = z == 0 ? w0 : z == 1 ? w1 : z == 2 ? w2 : w3;
    uint16_t* WT = wtout + (size_t)z * DM * DM;
    const int n0 = bx * 64, k0 = by * 64;
#pragma unroll
    for (int i = 0; i < 16; i++) {
      const int r = ty + i * 4;
      tile[r][tx] = f2b(W[(size_t)(k0 + r) * DM + n0 + tx]);
    }
    __syncthreads();
#pragma unroll
    for (int i = 0; i < 16; i++) {
      const int r = ty + i * 4;
      WT[(size_t)(n0 + r) * DM + k0 + tx] = tile[tx][r];
    }
  } else {
    const size_t i0 = ((size_t)(bid - 1024) * 256 + t) * 8;
    f32x4 a = *(const f32x4*)(x + i0);
    f32x4 b = *(const f32x4*)(x + i0 + 4);
    uint32_t o0 = f2b2(a[0], a[1]), o1 = f2b2(a[2], a[3]);
    uint32_t o2 = f2b2(b[0], b[1]), o3 = f2b2(b[2], b[3]);
    union { uint32_t u[4]; u16x8 v; } pk; pk.u[0] = o0; pk.u[1] = o1;
    pk.u[2] = o2; pk.u[3] = o3;
    *(u16x8*)(xb + i0) = pk.v;
  }
}

// ---------------- GEMM: C[M,1024] = A[M,1024] @ WT^T + bias ----------------
// MT x 128 tile, BK=32. Register-prefetch double-buffer; LDS unpadded + XOR
// swizzle slot(row,kc) = row*4 + (kc ^ ((row>>1)&3)) — 0 conflicts (r9).
// F32OUT: fp32 C-write. QKV: z0 scaled log2e/32, z2 written V^T [b][h][d][s].
template <int MT, bool F32OUT, bool QKV>
__global__ __launch_bounds__(256, 4) void gemm_bt(
    const uint16_t* __restrict__ A,       // [MR][DM] bf16
    const uint16_t* __restrict__ WTbase,  // z-th weight at z*DM*DM, [n][k]
    const float* __restrict__ bias0, const float* __restrict__ bias1,
    const float* __restrict__ bias2,
    void* __restrict__ o0, void* __restrict__ o1, void* __restrict__ o2)
{
  constexpr int NA = MT / 64;    // A staging slots per thread
  constexpr int NI = MT / 32;    // A frags per wave
  const int z = blockIdx.z;
  const uint16_t* WT   = WTbase + (size_t)z * DM * DM;
  const float*    bias = z == 0 ? bias0 : z == 1 ? bias1 : bias2;
  void*           Cout = z == 0 ? o0 : z == 1 ? o1 : o2;
  const float     sc   = (QKV && z == 0) ? 0.045084219f : 1.0f;

  __shared__ __align__(16) uint16_t Al[MT * 32];
  __shared__ __align__(16) uint16_t Bl[128 * 32];

  const int m0 = blockIdx.y * MT, n0 = blockIdx.x * 128;
  const int t = threadIdx.x;
  const int lane = t & 63, w = t >> 6;
  const int l15 = lane & 15, quad = lane >> 4;
  const int wm = (w >> 1) * (MT / 2), wn = (w & 1) * 64;

  const uint16_t* gA[NA];
  uint16_t*       lA[NA];
#pragma unroll
  for (int i = 0; i < NA; i++) {
    const int S = (w * NA + i) * 64 + lane;
    const int row = S >> 2;
    const int kc  = (S & 3) ^ ((row >> 1) & 3);
    gA[i] = A + (size_t)(m0 + row) * DM + kc * 8;
    lA[i] = &Al[S * 8];
  }
  const uint16_t* gB[2];
  uint16_t*       lB[2];
#pragma unroll
  for (int i = 0; i < 2; i++) {
    const int S = (w * 2 + i) * 64 + lane;
    const int row = S >> 2;
    const int kc  = (S & 3) ^ ((row >> 1) & 3);
    gB[i] = WT + (size_t)(n0 + row) * DM + kc * 8;
    lB[i] = &Bl[S * 8];
  }

  int offA[NI], offB[4];
#pragma unroll
  for (int i = 0; i < NI; i++) {
    const int ra = wm + i * 16 + l15;
    offA[i] = (ra * 4 + (quad ^ ((ra >> 1) & 3))) * 8;
  }
#pragma unroll
  for (int j = 0; j < 4; j++) {
    const int rb = wn + j * 16 + l15;
    offB[j] = (rb * 4 + (quad ^ ((rb >> 1) & 3))) * 8;
  }

  f32x4 acc[NI][4];
#pragma unroll
  for (int i = 0; i < NI; i++)
#pragma unroll
    for (int j = 0; j < 4; j++) acc[i][j] = {0.f, 0.f, 0.f, 0.f};

  s16x8 pa[NA], pb[2];
#pragma unroll
  for (int i = 0; i < NA; i++) pa[i] = *(const s16x8*)(gA[i]);
#pragma unroll
  for (int i = 0; i < 2; i++)  pb[i] = *(const s16x8*)(gB[i]);

  for (int k0 = 0; k0 < DM; k0 += 32) {
    __syncthreads();
#pragma unroll
    for (int i = 0; i < NA; i++) *(s16x8*)lA[i] = pa[i];
#pragma unroll
    for (int i = 0; i < 2; i++)  *(s16x8*)lB[i] = pb[i];
    __syncthreads();

    if (k0 + 32 < DM) {
#pragma unroll
      for (int i = 0; i < NA; i++) pa[i] = *(const s16x8*)(gA[i] + k0 + 32);
#pragma unroll
      for (int i = 0; i < 2; i++)  pb[i] = *(const s16x8*)(gB[i] + k0 + 32);
    }

    frag_t af[NI], bf[4];
#pragma unroll
    for (int i = 0; i < NI; i++) af[i] = *(const frag_t*)&Al[offA[i]];
#pragma unroll
    for (int j = 0; j < 4; j++)  bf[j] = *(const frag_t*)&Bl[offB[j]];
#pragma unroll
    for (int i = 0; i < NI; i++)
#pragma unroll
      for (int j = 0; j < 4; j++)
        acc[i][j] = mfma_16x16x32_bf16(af[i], bf[j], acc[i][j]);
  }

  // epilogue: C/D layout col=lane&15, row=quad*4+reg (verified m89/m91)
#pragma unroll
  for (int j = 0; j < 4; j++) {
    const int col = n0 + wn + j * 16 + l15;
    const float bv = bias[col];
#pragma unroll
    for (int i = 0; i < NI; i++) {
      const int row = m0 + wm + i * 16 + quad * 4;
      if (QKV && z == 2) {
        const int bb = row >> 11, s = row & 2047;
        const int hh = col >> 6,  dd = col & 63;
        union { uint32_t u[2]; u16x4 v; } pk;
        pk.u[0] = f2b2(acc[i][j][0] + bv, acc[i][j][1] + bv);
        pk.u[1] = f2b2(acc[i][j][2] + bv, acc[i][j][3] + bv);
        *(u16x4*)((uint16_t*)Cout +
                  (((size_t)bb * NH + hh) * DH + dd) * SEQ + s) = pk.v;
      } else {
#pragma unroll
        for (int r = 0; r < 4; r++) {
          const float val = (acc[i][j][r] + bv) * sc;
          if (F32OUT)
            ((float*)Cout)[(size_t)(row + r) * DM + col] = val;
          else
            ((uint16_t*)Cout)[(size_t)(row + r) * DM + col] = f2b(val);
        }
      }
    }
  }
}

// ---------------- MFMA flash attention, causal, 2-wave blocks ----------------
// Fixed-max softmax: s = (q*log2e/32)·k has |s| < ~2.2 => P = exp2(s) safe;
// per-lane row-sum, one cross-lane reduction per q-tile.
// Block = 128 thr (2 waves x 16 q-rows = 32-row q-tile) x one (b,h); pair
// (p, 63-p) => exactly 33 k-tile iters/block; grid 1024 = 4 blocks/CU.
// K/V LDS XOR-swizzled (slot' = slot ^ (row&7)): staging writes and frag
// reads conflict-free (GEMM-proven r9). P stored fp32, packed to bf16 frags
// on read via v_cvt_pk_bf16_f32 when available.
__global__ __launch_bounds__(128) void attn_mfma(
    const uint16_t* __restrict__ Q,   // [MR][DM] (pre-scaled by log2e/32)
    const uint16_t* __restrict__ K,   // [MR][DM]
    const uint16_t* __restrict__ Vt,  // [B*NH][DH][SEQ]
    uint16_t* __restrict__ O)         // [MR][DM] (may alias Q)
{
  __shared__ __align__(16) uint16_t Kl[64 * 64];   // swizzled, 8 KB
  __shared__ __align__(16) uint16_t Vl[64 * 64];
  __shared__ __align__(16) float    Pf[2 * 16 * 72];

  const int t = threadIdx.x;
  const int lane = t & 63, wave = t >> 6;   // wave 0/1
  const int l15 = lane & 15, quad = lane >> 4;
  const int pidx = blockIdx.x >> 5;         // 0..31
  const int bh = blockIdx.x & 31;
  const int b = bh >> 4, h = bh & 15;

  const uint16_t* Kg = K  + (size_t)(b * SEQ) * DM + h * DH;
  const uint16_t* Vg = Vt + (size_t)bh * DH * SEQ;
  float* Pw = Pf + wave * 16 * 72;

  // staging map: thread t -> row kr, global 64B chunk c0..c0+3 (contiguous),
  // LDS slot s' = kc ^ (kr&7)  (16B slots, 8 per row)
  const int kr = t >> 1;
  const int c0 = (t & 1) * 4;
  uint16_t* klw[4];
  uint16_t* vlw[4];
#pragma unroll
  for (int i = 0; i < 4; i++) {
    const int sp = (c0 + i) ^ (kr & 7);
    klw[i] = &Kl[kr * 64 + sp * 8];
    vlw[i] = &Vl[kr * 64 + sp * 8];
  }
  // frag read offsets: row = nt*16+l15, slot = ks*4+quad, s' = slot^(l15&7)
  int koff[2][4];
#pragma unroll
  for (int ks = 0; ks < 2; ks++)
#pragma unroll
    for (int nt = 0; nt < 4; nt++)
      koff[ks][nt] = (nt * 16 + l15) * 64 + (((ks * 4 + quad) ^ (l15 & 7)) * 8);

  for (int phase = 0; phase < 2; phase++) {
    const int p = phase == 0 ? pidx : 63 - pidx;
    const int q0 = p * 32;
    const int nkt = (p >> 1) + 1;

    // Q fragments (A-layout): rows q0+wave*16+l15, k = ks*32+quad*8
    frag_t qf[2];
    const uint16_t* qbase =
        Q + (size_t)(b * SEQ + q0 + wave * 16) * DM + h * DH;
#pragma unroll
    for (int ks = 0; ks < 2; ks++)
      qf[ks] = *(const frag_t*)(qbase + (size_t)l15 * DM + ks * 32 + quad * 8);

    f32x4 Oacc[4];
#pragma unroll
    for (int dt = 0; dt < 4; dt++) Oacc[dt] = {0.f, 0.f, 0.f, 0.f};
    float lsum[4] = {0.f, 0.f, 0.f, 0.f};

    // prefetch tile 0 (global reads unswizzled/coalesced)
    s16x8 ka[4], va[4];
#pragma unroll
    for (int i = 0; i < 4; i++) {
      ka[i] = *(const s16x8*)(Kg + (size_t)kr * DM + (c0 + i) * 8);
      va[i] = *(const s16x8*)(Vg + (size_t)kr * SEQ + (c0 + i) * 8);
    }

    for (int kt = 0; kt < nkt; kt++) {
      __syncthreads();   // previous tile's LDS reads complete
#pragma unroll
      for (int i = 0; i < 4; i++) {
        *(s16x8*)klw[i] = ka[i];
        *(s16x8*)vlw[i] = va[i];
      }
      __syncthreads();

      if (kt + 1 < nkt) {   // next tile's loads hide under compute below
#pragma unroll
        for (int i = 0; i < 4; i++) {
          ka[i] = *(const s16x8*)(Kg + (size_t)((kt + 1) * 64 + kr) * DM +
                                  (c0 + i) * 8);
          va[i] = *(const s16x8*)(Vg + (size_t)kr * SEQ + (kt + 1) * 64 +
                                  (c0 + i) * 8);
        }
      }

      // ---- S = Q K^T ----
      f32x4 S[4];
#pragma unroll
      for (int nt = 0; nt < 4; nt++) S[nt] = {0.f, 0.f, 0.f, 0.f};
#pragma unroll
      for (int ks = 0; ks < 2; ks++) {
        frag_t bf[4];
#pragma unroll
        for (int nt = 0; nt < 4; nt++)
          bf[nt] = *(const frag_t*)&Kl[koff[ks][nt]];
#pragma unroll
        for (int nt = 0; nt < 4; nt++)
          S[nt] = mfma_16x16x32_bf16(qf[ks], bf[nt], S[nt]);
      }

      // ---- P = exp2(S) (causal-masked -> 0), fp32 into LDS ----
      const bool diag = (kt == nkt - 1);
#pragma unroll
      for (int r = 0; r < 4; r++) {
        const int row = q0 + wave * 16 + quad * 4 + r;
#pragma unroll
        for (int nt = 0; nt < 4; nt++) {
          const int col = kt * 64 + nt * 16 + l15;
          float pv = exp2f(S[nt][r]);
          if (diag && col > row) pv = 0.f;
          lsum[r] += pv;
          Pw[(quad * 4 + r) * 72 + nt * 16 + l15] = pv;
        }
      }

      // ---- O += P V  (P read fp32 -> packed bf16 frag; V from LDS) ----
#pragma unroll
      for (int ks = 0; ks < 2; ks++) {
        const float* prow = &Pw[l15 * 72 + ks * 32 + quad * 8];
        f32x4 pa = *(const f32x4*)(prow);
        f32x4 pb = *(const f32x4*)(prow + 4);
        union { uint32_t u[4]; frag_t f; } cv;
        cv.u[0] = f2b2(pa[0], pa[1]); cv.u[1] = f2b2(pa[2], pa[3]);
        cv.u[2] = f2b2(pb[0], pb[1]); cv.u[3] = f2b2(pb[2], pb[3]);
        frag_t pf = cv.f;
        frag_t vf[4];
#pragma unroll
        for (int dt = 0; dt < 4; dt++)
          vf[dt] = *(const frag_t*)&Vl[koff[ks][dt]];
#pragma unroll
        for (int dt = 0; dt < 4; dt++)
          Oacc[dt] = mfma_16x16x32_bf16(pf, vf[dt], Oacc[dt]);
      }
    }

    // ---- l reduction over the 16-lane row groups ----
    float linv[4];
#pragma unroll
    for (int r = 0; r < 4; r++) {
      float l = lsum[r];
      l += __shfl_xor(l, 1);
      l += __shfl_xor(l, 2);
      l += __shfl_xor(l, 4);
      l += __shfl_xor(l, 8);
      linv[r] = 1.f / l;
    }

    // ---- epilogue: O /= l, write (C-layout) ----
    uint16_t* obase =
        O + (size_t)(b * SEQ + q0 + wave * 16) * DM + h * DH;
#pragma unroll
    for (int r = 0; r < 4; r++) {
      const int row = quad * 4 + r;
#pragma unroll
      for (int dt = 0; dt < 4; dt++)
        obase[(size_t)row * DM + dt * 16 + l15] = f2b(Oacc[dt][r] * linv[r]);
    }
  }
}

// ---------------- launch ----------------
// ws: WT (8 MB) + Qb (8 MB) + Kb (8 MB) = 24 MB.
// d_out (16 MiB fp32) double-duty: first 8 MiB = V^T (bf16), second 8 MiB =
// xb (bf16 x). Both dead before the final projection overwrites all of d_out.
// Attention output aliases Qb.
extern "C" void kernel_launch(void* const* d_in, const int* in_sizes, int n_in,
                              void* d_out, int out_size, void* d_ws, size_t ws_size,
                              hipStream_t stream) {
  const float* x  = (const float*)d_in[0];
  const float* Wq = (const float*)d_in[1];
  const float* bq = (const float*)d_in[2];
  const float* Wk = (const float*)d_in[3];
  const float* bk = (const float*)d_in[4];
  const float* Wv = (const float*)d_in[5];
  const float* bv = (const float*)d_in[6];
  const float* Wo = (const float*)d_in[7];
  const float* bo = (const float*)d_in[8];

  uint16_t* WT = (uint16_t*)d_ws;
  uint16_t* Qb = WT + (size_t)4 * DM * DM;
  uint16_t* Kb = Qb + (size_t)MR * DM;
  uint16_t* Vtb = (uint16_t*)d_out;                   // V^T [B*NH][DH][SEQ]
  uint16_t* xb  = (uint16_t*)d_out + (size_t)MR * DM; // bf16 x, upper 8 MiB

  prep_all<<<dim3(1024 + MR * DM / 2048), 256, 0, stream>>>(
      Wq, Wk, Wv, Wo, WT, x, xb);
  gemm_bt<128, false, true><<<dim3(8, 32, 3), 256, 0, stream>>>(
      xb, WT, bq, bk, bv, Qb, Kb, Vtb);
  attn_mfma<<<dim3(1024), 128, 0, stream>>>(Qb, Kb, Vtb, Qb);
  gemm_bt<64, true, false><<<dim3(8, 64, 1), 256, 0, stream>>>(
      Qb, WT + (size_t)3 * DM * DM, bo, bo, bo, d_out, d_out, d_out);
}